// Round 9
// baseline (66.612 us; speedup 1.0000x reference)
//
#include <hip/hip_runtime.h>
#include <hip/hip_bf16.h>

#define D_N 512
#define M_N 1024
#define F_N 64
#define L2E 1.442695041f

__device__ __forceinline__ float wred_sum(float p) {
#pragma unroll
    for (int off = 32; off > 0; off >>= 1) p += __shfl_xor(p, off, 64);
    return p;
}

// q[lane] = sum_k att[k] * W[k][lane]  (one wave)
__device__ __forceinline__ float proj_col(const float* __restrict__ gw,
                                          const float* __restrict__ att,
                                          int lane) {
    float acc = 0.f;
#pragma unroll
    for (int k = 0; k < 64; ++k)
        acc += att[k] * gw[k * 64 + lane];
    return acc;
}

// serial 64-dot of a global row with an LDS 64-vector (float4 path)
__device__ __forceinline__ float dot64(const float* __restrict__ row,
                                       const float* __restrict__ q) {
    const float4* r4 = (const float4*)row;
    const float4* q4 = (const float4*)q;
    float a0 = 0.f, a1 = 0.f, a2 = 0.f, a3 = 0.f;
#pragma unroll
    for (int i = 0; i < 16; ++i) {
        float4 x = r4[i], y = q4[i];
        a0 += x.x * y.x; a1 += x.y * y.y; a2 += x.z * y.z; a3 += x.w * y.w;
    }
    return (a0 + a1) + (a2 + a3);
}

// ---------------------------------------------------------------------------
// kbig (144 blocks x 512 thr), all block groups fully independent:
//  blocks   0..63 : 8 edges each (wave/edge): umed in-block, softmax denom,
//                   self-term partials -> e1dp/e2dp[b]
//  blocks  64..95 : 32 meds each: recompute ALL 512 edge scalars locally,
//                   g-weights, embedding-space sums -> e1p/e2p[b-64]
//  blocks 96..143 : partial gathers -> pp  (P0[0,16) MC[16,32) P1[32,64) MM[64,96))
// ---------------------------------------------------------------------------
__global__ __launch_bounds__(512) void kbig(
    const int* __restrict__ c_it, const int* __restrict__ m_it,
    const float* __restrict__ c_emb, const float* __restrict__ m_emb,
    const float* __restrict__ pe0, const float* __restrict__ pe1,
    const float* __restrict__ gat_w, const float* __restrict__ gat_att,
    const float* __restrict__ hattr,
    float* __restrict__ e1dp, float* __restrict__ e2dp,
    float* __restrict__ e1p, float* __restrict__ e2p,
    float* __restrict__ pp)
{
    __shared__ __align__(16) float q1s[64];
    __shared__ __align__(16) float q2s[64];
    __shared__ __align__(16) float umed[M_N];
    __shared__ float sV[D_N], sC1[D_N], sC2[D_N];
    __shared__ float sG1[32], sG2[32];
    __shared__ float redA[8][64], redB[8][64];
    const int b = blockIdx.x, tid = threadIdx.x;
    const int w = tid >> 6, lane = tid & 63;

    if (b < 96) {
        // ---- shared preamble for edge & med paths: q1, q2, umed ----
        if (w == 0) q1s[lane] = proj_col(gat_w, gat_att, lane);
        else if (w == 1) q2s[lane] = proj_col(gat_w, gat_att + 64, lane);
        __syncthreads();
#pragma unroll
        for (int i = 0; i < 2; ++i) {
            int m = tid + i * 512;
            umed[m] = L2E * dot64(m_emb + (size_t)m_it[m] * F_N, q1s);
        }
        __syncthreads();

        if (b < 64) {
            // ---------------- edge path: 8 edges, wave per edge ----------------
            const int e = b * 8 + w;
            const float xe = c_emb[(size_t)c_it[e] * F_N + lane];
            const float v  = L2E * wred_sum(hattr[(size_t)e * F_N + lane] * q2s[lane]);
            const float us = L2E * wred_sum(xe * q1s[lane]);
            float s = 0.f;
#pragma unroll
            for (int i = 0; i < 16; ++i) {
                float a = umed[i * 64 + lane] + v;
                a = fmaxf(a, 0.2f * a);
                s += exp2f(a);
            }
            s = wred_sum(s);
            float asf = us + v; asf = fmaxf(asf, 0.2f * asf);
            const float exs = exp2f(asf);
            const float denom = s + exs;
            const float asel = exs / denom;
            const float rd = 1.f / (denom * (float)(M_N + 1));
            const float w1a = asel * rd * exs;
            const float w2a = (1.f - asel) * rd * exs;
            redA[w][lane] = w1a * xe;
            redB[w][lane] = w2a * xe;
            __syncthreads();
            if (w == 0) {
                float sa = 0.f, sbv = 0.f;
#pragma unroll
                for (int i = 0; i < 8; ++i) { sa += redA[i][lane]; sbv += redB[i][lane]; }
                e1dp[b * 64 + lane] = sa;
                e2dp[b * 64 + lane] = sbv;
            }
        } else {
            // ---------------- med path: recompute all edge scalars -------------
            const int mb = b - 64;              // med block 0..31
            const int m_base = mb * 32;
            {
                const int t = tid;              // one edge per thread
                const float v  = L2E * dot64(hattr + (size_t)t * F_N, q2s);
                const float us = L2E * dot64(c_emb + (size_t)c_it[t] * F_N, q1s);
                const float4* u4 = (const float4*)umed;
                float s = 0.f;
#pragma unroll 4
                for (int i = 0; i < 256; ++i) {
                    float4 uv = u4[i];
                    float a0 = uv.x + v; a0 = fmaxf(a0, 0.2f * a0); s += exp2f(a0);
                    float a1 = uv.y + v; a1 = fmaxf(a1, 0.2f * a1); s += exp2f(a1);
                    float a2 = uv.z + v; a2 = fmaxf(a2, 0.2f * a2); s += exp2f(a2);
                    float a3 = uv.w + v; a3 = fmaxf(a3, 0.2f * a3); s += exp2f(a3);
                }
                float asf = us + v; asf = fmaxf(asf, 0.2f * asf);
                const float exs = exp2f(asf);
                const float denom = s + exs;
                const float asel = exs / denom;
                const float rd = 1.f / (denom * (float)(M_N + 1));
                sV[t]  = v;
                sC1[t] = asel * rd;
                sC2[t] = (1.f - asel) * rd;
            }
            __syncthreads();
            // g-weights for this block's 32 meds (16 threads per med)
            {
                const int mi = tid >> 4, l16 = tid & 15;
                const float um = umed[m_base + mi];
                float gA = 0.f, gB = 0.f;
#pragma unroll 4
                for (int i = 0; i < 32; ++i) {
                    int e = l16 + i * 16;
                    float a = um + sV[e];
                    a = fmaxf(a, 0.2f * a);
                    float ex = exp2f(a);
                    gA += sC1[e] * ex;
                    gB += sC2[e] * ex;
                }
#pragma unroll
                for (int off = 1; off < 16; off <<= 1) {
                    gA += __shfl_xor(gA, off, 64);
                    gB += __shfl_xor(gB, off, 64);
                }
                if (l16 == 0) { sG1[mi] = gA; sG2[mi] = gB; }
            }
            __syncthreads();
            // embedding-space weighted sums (8 waves x 4 meds)
            float a1 = 0.f, a2 = 0.f;
#pragma unroll
            for (int j = 0; j < 4; ++j) {
                int ml = w * 4 + j;
                float x = m_emb[(size_t)m_it[m_base + ml] * F_N + lane];
                a1 += sG1[ml] * x;
                a2 += sG2[ml] * x;
            }
            redA[w][lane] = a1; redB[w][lane] = a2;
            __syncthreads();
            if (w == 0) {
                float sa = 0.f, sbv = 0.f;
#pragma unroll
                for (int i = 0; i < 8; ++i) { sa += redA[i][lane]; sbv += redB[i][lane]; }
                e1p[mb * 64 + lane] = sa;
                e2p[mb * 64 + lane] = sbv;
            }
        }
    } else {
        // ---------------- gather path ----------------
        const int g = b - 96;
        const int* idx; const float* ta; const float* tb;
        int base_r, oA, oB;
        if (g < 16) { idx = c_it; ta = pe0; tb = c_emb; base_r = g * 32; oA = g; oB = 16 + g; }
        else { int g2 = g - 16; idx = m_it; ta = pe1; tb = m_emb; base_r = g2 * 32; oA = 32 + g2; oB = 64 + g2; }
        const int r0 = base_r + w * 4;
        float a = 0.f, bb = 0.f;
#pragma unroll
        for (int j = 0; j < 4; ++j) {
            int r = idx[r0 + j];
            a  += ta[(size_t)r * F_N + lane];
            bb += tb[(size_t)r * F_N + lane];
        }
        redA[w][lane] = a; redB[w][lane] = bb;
        __syncthreads();
        if (w == 0) {
            float sa = 0.f, sbv = 0.f;
#pragma unroll
            for (int i = 0; i < 8; ++i) { sa += redA[i][lane]; sbv += redB[i][lane]; }
            pp[oA * 64 + lane] = sa;
            pp[oB * 64 + lane] = sbv;
        }
    }
}

// ---------------------------------------------------------------------------
// kfin: single-block finisher: fold partials, S = E @ W^T, conv matvecs, lin.
// ---------------------------------------------------------------------------
__global__ __launch_bounds__(256) void kfin(
    const float* __restrict__ conv_w, const float* __restrict__ conv_b,
    const float* __restrict__ gat_w, const float* __restrict__ gat_b,
    const float* __restrict__ lin_w,
    const float* __restrict__ pp,
    const float* __restrict__ e1p, const float* __restrict__ e2p,
    const float* __restrict__ e1dp, const float* __restrict__ e2dp,
    float* __restrict__ out)
{
    __shared__ float sE1[64], sE2[64], sP0[64], sP1[64], sMC[64], sMM[64];
    __shared__ float sS1[64], sS2[64];
    __shared__ float sRepD[128], sRepM[128];
    __shared__ float sWt[64 * 65];
    __shared__ float sLt[128 * 65];
    const int tid = threadIdx.x, w = tid >> 6, lane = tid & 63;

    if (w == 0) {
        float a = 0.f;
#pragma unroll
        for (int i = 0; i < 32; ++i) a += e1p[i * 64 + lane];
#pragma unroll
        for (int i = 0; i < 64; ++i) a += e1dp[i * 64 + lane];
        sE1[lane] = a;
    } else if (w == 1) {
        float a = 0.f;
#pragma unroll
        for (int i = 0; i < 32; ++i) a += e2p[i * 64 + lane];
#pragma unroll
        for (int i = 0; i < 64; ++i) a += e2dp[i * 64 + lane];
        sE2[lane] = a;
    } else if (w == 2) {
        float a = 0.f, c = 0.f;
#pragma unroll
        for (int i = 0; i < 16; ++i) { a += pp[i * 64 + lane]; c += pp[(16 + i) * 64 + lane]; }
        sP0[lane] = a; sMC[lane] = c * (1.f / (float)D_N);
    } else {
        float a = 0.f, c = 0.f;
#pragma unroll
        for (int i = 0; i < 32; ++i) { a += pp[(32 + i) * 64 + lane]; c += pp[(64 + i) * 64 + lane]; }
        sP1[lane] = a; sMM[lane] = c * (1.f / (float)M_N);
    }
    for (int i = tid; i < 4096; i += 256)
        sWt[(i & 63) * 65 + (i >> 6)] = gat_w[i];          // sWt[j*65+k]=W[k][j]
    for (int i = tid; i < 8192; i += 256) {
        int k = i >> 7, j = i & 127;
        sLt[j * 65 + k] = lin_w[i];                        // sLt[j*65+k]=lin_w[k][j]
    }
    __syncthreads();
    if (tid < 64) {
        float s1 = 0.f, s2 = 0.f;
#pragma unroll 8
        for (int j = 0; j < 64; ++j) {
            s1 += sE1[j] * sWt[j * 65 + lane];
            s2 += sE2[j] * sWt[j * 65 + lane];
        }
        sS1[lane] = s1;
        sS2[lane] = s2 * (1.f / (float)D_N);
    }
    __syncthreads();
    for (int i = tid; i < 4096; i += 256)
        sWt[(i & 63) * 65 + (i >> 6)] = conv_w[i];
    __syncthreads();
    if (tid < 64) {
        float dia = conv_b[lane], med = conv_b[lane];
#pragma unroll 8
        for (int j = 0; j < 64; ++j) {
            dia += sMC[j] * sWt[j * 65 + lane];
            med += sMM[j] * sWt[j * 65 + lane];
        }
        sRepD[lane]      = sS1[lane] + (float)D_N * gat_b[lane];
        sRepD[64 + lane] = (float)D_N * dia;
        sRepM[lane]      = sS2[lane] + (float)M_N * gat_b[lane];
        sRepM[64 + lane] = (float)M_N * med;
    }
    __syncthreads();
    if (tid < 64) {
        float o1 = sP0[lane], o2 = sP1[lane];
#pragma unroll 8
        for (int j = 0; j < 128; ++j) {
            o1 += sRepD[j] * sLt[j * 65 + lane];
            o2 += sRepM[j] * sLt[j * 65 + lane];
        }
        out[lane] = o1;
        out[64 + lane] = o2;
    }
}

extern "C" void kernel_launch(void* const* d_in, const int* in_sizes, int n_in,
                              void* d_out, int out_size, void* d_ws, size_t ws_size,
                              hipStream_t stream) {
    const int*   c_it    = (const int*)d_in[0];
    const int*   m_it    = (const int*)d_in[1];
    const float* c_emb   = (const float*)d_in[2];
    const float* m_emb   = (const float*)d_in[3];
    const float* pe0     = (const float*)d_in[4];
    const float* pe1     = (const float*)d_in[5];
    const float* conv_w  = (const float*)d_in[6];
    const float* conv_b  = (const float*)d_in[7];
    const float* gat_w   = (const float*)d_in[8];
    const float* gat_b   = (const float*)d_in[9];
    const float* gat_att = (const float*)d_in[10];
    const float* hattr   = (const float*)d_in[11];
    const float* lin_w   = (const float*)d_in[12];
    float* out = (float*)d_out;

    float* ws   = (float*)d_ws;
    float* pp   = ws;                 // 96*64
    float* e1p  = pp + 96 * 64;       // 32*64
    float* e2p  = e1p + 32 * 64;      // 32*64
    float* e1dp = e2p + 32 * 64;      // 64*64
    float* e2dp = e1dp + 64 * 64;     // 64*64

    kbig<<<144, 512, 0, stream>>>(c_it, m_it, c_emb, m_emb, pe0, pe1,
                                  gat_w, gat_att, hattr,
                                  e1dp, e2dp, e1p, e2p, pp);
    kfin<<<1, 256, 0, stream>>>(conv_w, conv_b, gat_w, gat_b, lin_w,
                                pp, e1p, e2p, e1dp, e2dp, out);
}

// Round 10
// 27.395 us; speedup vs baseline: 2.4316x; 2.4316x over previous
//
#include <hip/hip_runtime.h>
#include <hip/hip_bf16.h>

#define D_N 512
#define M_N 1024
#define F_N 64
#define L2E 1.442695041f

__device__ __forceinline__ float wred_sum(float p) {
#pragma unroll
    for (int off = 32; off > 0; off >>= 1) p += __shfl_xor(p, off, 64);
    return p;
}

// q[lane] = sum_k att[k] * W[k][lane]  (one wave)
__device__ __forceinline__ float proj_col(const float* __restrict__ gw,
                                          const float* __restrict__ att,
                                          int lane) {
    float acc = 0.f;
#pragma unroll
    for (int k = 0; k < 64; ++k)
        acc += att[k] * gw[k * 64 + lane];
    return acc;
}

// ---------------------------------------------------------------------------
// n1 kprep (64 blocks x 512):
//  b 0..15 : c-gathers rows [b*32,b*32+32): pp P0[b], MC[16+b]; uc[row] dots
//  b 16..47: m-gathers rows [(b-16)*32, +32): pp P1[32+g2], MM[64+g2]; umed dots
//  b 48..63: hattr dots: v[row] for rows [(b-48)*32, +32)
// ---------------------------------------------------------------------------
__global__ __launch_bounds__(512) void kprep(
    const int* __restrict__ c_it, const int* __restrict__ m_it,
    const float* __restrict__ c_emb, const float* __restrict__ m_emb,
    const float* __restrict__ pe0, const float* __restrict__ pe1,
    const float* __restrict__ gat_w, const float* __restrict__ gat_att,
    const float* __restrict__ hattr,
    float* __restrict__ umed, float* __restrict__ uc, float* __restrict__ v,
    float* __restrict__ pp)
{
    __shared__ __align__(16) float qs[64];
    __shared__ float redA[8][64], redB[8][64];
    const int b = blockIdx.x, tid = threadIdx.x;
    const int w = tid >> 6, lane = tid & 63;

    if (b < 48) {
        if (w == 0) qs[lane] = proj_col(gat_w, gat_att, lane);   // q1
        __syncthreads();
        const int* idx; const float* ta; const float* tb;
        float* dout; int base_r, oA, oB;
        if (b < 16) { idx = c_it; ta = pe0; tb = c_emb; dout = uc;
                      base_r = b * 32; oA = b; oB = 16 + b; }
        else { int g2 = b - 16; idx = m_it; ta = pe1; tb = m_emb; dout = umed;
               base_r = g2 * 32; oA = 32 + g2; oB = 64 + g2; }
        const int r0 = base_r + w * 4;
        float a = 0.f, bb = 0.f;
#pragma unroll
        for (int j = 0; j < 4; ++j) {
            const int row = r0 + j;
            const int r = idx[row];
            float av = ta[(size_t)r * F_N + lane];
            float bv = tb[(size_t)r * F_N + lane];
            a += av; bb += bv;
            float d = wred_sum(bv * qs[lane]);
            if (lane == 0) dout[row] = L2E * d;
        }
        redA[w][lane] = a; redB[w][lane] = bb;
        __syncthreads();
        if (w == 0) {
            float sa = 0.f, sbv = 0.f;
#pragma unroll
            for (int i = 0; i < 8; ++i) { sa += redA[i][lane]; sbv += redB[i][lane]; }
            pp[oA * 64 + lane] = sa;
            pp[oB * 64 + lane] = sbv;
        }
    } else {
        if (w == 0) qs[lane] = proj_col(gat_w, gat_att + 64, lane);  // q2
        __syncthreads();
        const int r0 = (b - 48) * 32 + w * 4;
#pragma unroll
        for (int j = 0; j < 4; ++j) {
            const int row = r0 + j;
            float hv = hattr[(size_t)row * F_N + lane];
            float d = wred_sum(hv * qs[lane]);
            if (lane == 0) v[row] = L2E * d;
        }
    }
}

// ---------------------------------------------------------------------------
// n2 kedge (16 blocks x 512): 32 edges/block, wave handles 4 edges.
//  Per edge: softmax denominator over umed (LDS) -> c1f,c2f; accumulate
//  self-term partials e1dp/e2dp[b] = sum_e w{1,2}a * c_emb[c_it[e]].
// ---------------------------------------------------------------------------
__global__ __launch_bounds__(512) void kedge(
    const int* __restrict__ c_it, const float* __restrict__ c_emb,
    const float* __restrict__ umed_g, const float* __restrict__ uc,
    const float* __restrict__ v,
    float* __restrict__ c1f, float* __restrict__ c2f,
    float* __restrict__ e1dp, float* __restrict__ e2dp)
{
    __shared__ float umed[M_N];
    __shared__ float redA[8][64], redB[8][64];
    const int b = blockIdx.x, tid = threadIdx.x;
    const int w = tid >> 6, lane = tid & 63;

    umed[tid] = umed_g[tid];
    umed[tid + 512] = umed_g[tid + 512];
    __syncthreads();

    float accA = 0.f, accB = 0.f;
#pragma unroll
    for (int ee = 0; ee < 4; ++ee) {
        const int e = b * 32 + w * 4 + ee;
        const float ve = v[e];
        float s = 0.f;
#pragma unroll
        for (int i = 0; i < 16; ++i) {
            float a = umed[i * 64 + lane] + ve;
            a = fmaxf(a, 0.2f * a);
            s += exp2f(a);
        }
        s = wred_sum(s);
        float asf = uc[e] + ve; asf = fmaxf(asf, 0.2f * asf);
        const float exs = exp2f(asf);
        const float denom = s + exs;
        const float asel = exs / denom;
        const float rd = 1.f / (denom * (float)(M_N + 1));
        if (lane == 0) {
            c1f[e] = asel * rd;
            c2f[e] = (1.f - asel) * rd;
        }
        const float w1a = asel * rd * exs;
        const float w2a = (1.f - asel) * rd * exs;
        const float xe = c_emb[(size_t)c_it[e] * F_N + lane];
        accA += w1a * xe;
        accB += w2a * xe;
    }
    redA[w][lane] = accA; redB[w][lane] = accB;
    __syncthreads();
    if (w == 0) {
        float sa = 0.f, sbv = 0.f;
#pragma unroll
        for (int i = 0; i < 8; ++i) { sa += redA[i][lane]; sbv += redB[i][lane]; }
        e1dp[b * 64 + lane] = sa;
        e2dp[b * 64 + lane] = sbv;
    }
}

// ---------------------------------------------------------------------------
// n3 kmed (32 blocks x 512): 32 meds/block. g1/g2 per med over 512 edges,
//  then embedding-space weighted sums -> e1p/e2p[b].
// ---------------------------------------------------------------------------
__global__ __launch_bounds__(512) void kmed(
    const int* __restrict__ m_it, const float* __restrict__ m_emb,
    const float* __restrict__ umed_g, const float* __restrict__ v,
    const float* __restrict__ c1f, const float* __restrict__ c2f,
    float* __restrict__ e1p, float* __restrict__ e2p)
{
    __shared__ float sV[D_N], sC1[D_N], sC2[D_N];
    __shared__ float sUm[32], sG1[32], sG2[32];
    __shared__ float redA[8][64], redB[8][64];
    const int b = blockIdx.x, tid = threadIdx.x;
    const int w = tid >> 6, lane = tid & 63;
    const int m_base = b * 32;

    sV[tid] = v[tid]; sC1[tid] = c1f[tid]; sC2[tid] = c2f[tid];
    if (tid < 32) sUm[tid] = umed_g[m_base + tid];
    __syncthreads();

    {
        const int mi = tid >> 4, l16 = tid & 15;
        const float um = sUm[mi];
        float gA = 0.f, gB = 0.f;
#pragma unroll 4
        for (int i = 0; i < 32; ++i) {
            int e = l16 + i * 16;
            float a = um + sV[e];
            a = fmaxf(a, 0.2f * a);
            float ex = exp2f(a);
            gA += sC1[e] * ex;
            gB += sC2[e] * ex;
        }
#pragma unroll
        for (int off = 1; off < 16; off <<= 1) {
            gA += __shfl_xor(gA, off, 64);
            gB += __shfl_xor(gB, off, 64);
        }
        if (l16 == 0) { sG1[mi] = gA; sG2[mi] = gB; }
    }
    __syncthreads();
    float a1 = 0.f, a2 = 0.f;
#pragma unroll
    for (int j = 0; j < 4; ++j) {
        int ml = w * 4 + j;
        float x = m_emb[(size_t)m_it[m_base + ml] * F_N + lane];
        a1 += sG1[ml] * x;
        a2 += sG2[ml] * x;
    }
    redA[w][lane] = a1; redB[w][lane] = a2;
    __syncthreads();
    if (w == 0) {
        float sa = 0.f, sbv = 0.f;
#pragma unroll
        for (int i = 0; i < 8; ++i) { sa += redA[i][lane]; sbv += redB[i][lane]; }
        e1p[b * 64 + lane] = sa;
        e2p[b * 64 + lane] = sbv;
    }
}

// ---------------------------------------------------------------------------
// n4 kfin: single-block finisher.
// ---------------------------------------------------------------------------
__global__ __launch_bounds__(256) void kfin(
    const float* __restrict__ conv_w, const float* __restrict__ conv_b,
    const float* __restrict__ gat_w, const float* __restrict__ gat_b,
    const float* __restrict__ lin_w,
    const float* __restrict__ pp,
    const float* __restrict__ e1p, const float* __restrict__ e2p,
    const float* __restrict__ e1dp, const float* __restrict__ e2dp,
    float* __restrict__ out)
{
    __shared__ float sE1[64], sE2[64], sP0[64], sP1[64], sMC[64], sMM[64];
    __shared__ float sS1[64], sS2[64];
    __shared__ float sRepD[128], sRepM[128];
    __shared__ float sWt[64 * 65];
    __shared__ float sLt[128 * 65];
    const int tid = threadIdx.x, w = tid >> 6, lane = tid & 63;

    if (w == 0) {
        float a = 0.f;
#pragma unroll
        for (int i = 0; i < 32; ++i) a += e1p[i * 64 + lane];
#pragma unroll
        for (int i = 0; i < 16; ++i) a += e1dp[i * 64 + lane];
        sE1[lane] = a;
    } else if (w == 1) {
        float a = 0.f;
#pragma unroll
        for (int i = 0; i < 32; ++i) a += e2p[i * 64 + lane];
#pragma unroll
        for (int i = 0; i < 16; ++i) a += e2dp[i * 64 + lane];
        sE2[lane] = a;
    } else if (w == 2) {
        float a = 0.f, c = 0.f;
#pragma unroll
        for (int i = 0; i < 16; ++i) { a += pp[i * 64 + lane]; c += pp[(16 + i) * 64 + lane]; }
        sP0[lane] = a; sMC[lane] = c * (1.f / (float)D_N);
    } else {
        float a = 0.f, c = 0.f;
#pragma unroll
        for (int i = 0; i < 32; ++i) { a += pp[(32 + i) * 64 + lane]; c += pp[(64 + i) * 64 + lane]; }
        sP1[lane] = a; sMM[lane] = c * (1.f / (float)M_N);
    }
    for (int i = tid; i < 4096; i += 256)
        sWt[(i & 63) * 65 + (i >> 6)] = gat_w[i];          // sWt[j*65+k]=W[k][j]
    for (int i = tid; i < 8192; i += 256) {
        int k = i >> 7, j = i & 127;
        sLt[j * 65 + k] = lin_w[i];                        // sLt[j*65+k]=lin_w[k][j]
    }
    __syncthreads();
    if (tid < 64) {
        float s1 = 0.f, s2 = 0.f;
#pragma unroll 8
        for (int j = 0; j < 64; ++j) {
            s1 += sE1[j] * sWt[j * 65 + lane];
            s2 += sE2[j] * sWt[j * 65 + lane];
        }
        sS1[lane] = s1;
        sS2[lane] = s2 * (1.f / (float)D_N);
    }
    __syncthreads();
    for (int i = tid; i < 4096; i += 256)
        sWt[(i & 63) * 65 + (i >> 6)] = conv_w[i];
    __syncthreads();
    if (tid < 64) {
        float dia = conv_b[lane], med = conv_b[lane];
#pragma unroll 8
        for (int j = 0; j < 64; ++j) {
            dia += sMC[j] * sWt[j * 65 + lane];
            med += sMM[j] * sWt[j * 65 + lane];
        }
        sRepD[lane]      = sS1[lane] + (float)D_N * gat_b[lane];
        sRepD[64 + lane] = (float)D_N * dia;
        sRepM[lane]      = sS2[lane] + (float)M_N * gat_b[lane];
        sRepM[64 + lane] = (float)M_N * med;
    }
    __syncthreads();
    if (tid < 64) {
        float o1 = sP0[lane], o2 = sP1[lane];
#pragma unroll 8
        for (int j = 0; j < 128; ++j) {
            o1 += sRepD[j] * sLt[j * 65 + lane];
            o2 += sRepM[j] * sLt[j * 65 + lane];
        }
        out[lane] = o1;
        out[64 + lane] = o2;
    }
}

extern "C" void kernel_launch(void* const* d_in, const int* in_sizes, int n_in,
                              void* d_out, int out_size, void* d_ws, size_t ws_size,
                              hipStream_t stream) {
    const int*   c_it    = (const int*)d_in[0];
    const int*   m_it    = (const int*)d_in[1];
    const float* c_emb   = (const float*)d_in[2];
    const float* m_emb   = (const float*)d_in[3];
    const float* pe0     = (const float*)d_in[4];
    const float* pe1     = (const float*)d_in[5];
    const float* conv_w  = (const float*)d_in[6];
    const float* conv_b  = (const float*)d_in[7];
    const float* gat_w   = (const float*)d_in[8];
    const float* gat_b   = (const float*)d_in[9];
    const float* gat_att = (const float*)d_in[10];
    const float* hattr   = (const float*)d_in[11];
    const float* lin_w   = (const float*)d_in[12];
    float* out = (float*)d_out;

    float* ws   = (float*)d_ws;
    float* umed = ws;                 // 1024
    float* uc   = umed + M_N;         // 512
    float* v    = uc + D_N;           // 512
    float* c1f  = v + D_N;            // 512
    float* c2f  = c1f + D_N;          // 512
    float* pp   = c2f + D_N;          // 96*64
    float* e1p  = pp + 96 * 64;       // 32*64
    float* e2p  = e1p + 32 * 64;      // 32*64
    float* e1dp = e2p + 32 * 64;      // 16*64
    float* e2dp = e1dp + 16 * 64;     // 16*64

    kprep<<<64, 512, 0, stream>>>(c_it, m_it, c_emb, m_emb, pe0, pe1,
                                  gat_w, gat_att, hattr, umed, uc, v, pp);
    kedge<<<16, 512, 0, stream>>>(c_it, c_emb, umed, uc, v,
                                  c1f, c2f, e1dp, e2dp);
    kmed<<<32, 512, 0, stream>>>(m_it, m_emb, umed, v, c1f, c2f, e1p, e2p);
    kfin<<<1, 256, 0, stream>>>(conv_w, conv_b, gat_w, gat_b, lin_w,
                                pp, e1p, e2p, e1dp, e2dp, out);
}